// Round 5
// baseline (220.215 us; speedup 1.0000x reference)
//
#include <hip/hip_runtime.h>

// FBPinn 1D, NW=16 windows, MLP 1->64->64->64->1 (tanh), sigmoid windows.
//   pass1: bucket point indices per window via LDS histogram + one global
//          atomic per (window, block); 1024-thr blocks (98 blocks -> 4x fewer
//          serialized atomics/line than 391). Also zeroes out[].
//   pass2: one window per block-column; a[64] accumulators in VGPRs (static),
//          h staged in per-thread LDS column (dynamic ii indexing), weights
//          streamed through SGPRs (scalar loads, uniform address), ii ROLLED.
//   [R2: dynamic h[ii] -> scratch 94MB, 73us]
//   [R3: full unroll -> 40KB body > 32KB I$, VALUBusy 12%, 186us]
//   [R4: unroll-4 ii -> 256 weights in flight > SGPR file -> VGPR spill,
//        WRITE 119MB, 76us]  => unroll 1: 64 weights = s_load bursts, fits.
//   __launch_bounds__(256,2): LDS caps occupancy at 2 waves/SIMD anyway; give
//   the allocator 256 VGPRs so spilling is impossible.
// Workspace: int cnt[16*16] (64B stride/window) @0, int list[16*CAP] @1024.

#define NW    16
#define NEUR  64
#define BLK   256
#define CAP   10240
#define CSTR  16          // cnt stride in ints -> 64B, one cacheline/window

__device__ __forceinline__ float fast_tanh(float x) {
    float e = __expf(x + x);
    return 1.0f - 2.0f * __builtin_amdgcn_rcpf(e + 1.0f);
}
__device__ __forceinline__ float fast_sigmoid(float z) {
    return __builtin_amdgcn_rcpf(1.0f + __expf(-z));
}

__global__ __launch_bounds__(1024) void pass1_bucket(
    const float* __restrict__ x, int n,
    int* __restrict__ cnt, int* __restrict__ list,
    float* __restrict__ out) {
    __shared__ int lcnt[NW];
    __shared__ int lbase[NW];
    const int tid = threadIdx.x;
    if (tid < NW) lcnt[tid] = 0;
    __syncthreads();

    const int i = blockIdx.x * 1024 + tid;
    int w0 = -1, w1 = -1, p0 = 0, p1 = 0;
    if (i < n) {
        out[i] = 0.0f;                    // fold d_out zeroing into pass1
        float xv = x[i];
        #pragma unroll
        for (int w = 0; w < NW; ++w) {
            float lo = (w == 0)      ? 0.0f   : ((float)w - 0.125f) * 6.25f;
            float hi = (w == NW - 1) ? 100.0f : ((float)w + 1.125f) * 6.25f;
            if (lo < xv && xv < hi) {     // exact strict compares
                if (w0 < 0) w0 = w; else w1 = w;
            }
        }
        if (w0 >= 0) p0 = atomicAdd(&lcnt[w0], 1);
        if (w1 >= 0) p1 = atomicAdd(&lcnt[w1], 1);
    }
    __syncthreads();
    if (tid < NW)
        lbase[tid] = atomicAdd(&cnt[tid * CSTR], lcnt[tid]);
    __syncthreads();

    if (w0 >= 0) { int p = lbase[w0] + p0; if (p < CAP) list[w0 * CAP + p] = i; }
    if (w1 >= 0) { int p = lbase[w1] + p1; if (p < CAP) list[w1 * CAP + p] = i; }
}

__global__ __launch_bounds__(256, 2) void pass2_mlp(
    const float* __restrict__ x,
    const float* __restrict__ W_in, const float* __restrict__ b_in,
    const float* __restrict__ W_h,  const float* __restrict__ b_h,
    const float* __restrict__ W_out, const float* __restrict__ b_out,
    const int* __restrict__ cnt, const int* __restrict__ list,
    float* __restrict__ out) {
    __shared__ float hbuf[NEUR * BLK];            // 64 KB, column per thread
    const int tid = threadIdx.x;
    const int w   = blockIdx.y;                   // window id: wave-uniform
    const int count = min(cnt[w * CSTR], CAP);

    float lo = (w == 0)      ? 0.0f   : ((float)w - 0.125f) * 6.25f;
    float hi = (w == NW - 1) ? 100.0f : ((float)w + 1.125f) * 6.25f;
    float mean    = 0.5f * (lo + hi);
    float inv_std = 1.0f / (0.5f * (hi - lo));
    float ow0 = (float)w * 6.25f;                 // ovm[w] exactly
    float ow1 = (float)(w + 1) * 6.25f;

    const float* Wi = W_in  + w * NEUR;
    const float* bi = b_in  + w * NEUR;
    const float* W0 = W_h   + (0 * NW + w) * NEUR * NEUR;
    const float* b0 = b_h   + (0 * NW + w) * NEUR;
    const float* W1 = W_h   + (1 * NW + w) * NEUR * NEUR;
    const float* b1 = b_h   + (1 * NW + w) * NEUR;
    const float* Wo = W_out + w * NEUR;
    const float bo  = b_out[w];

    for (int base = blockIdx.x * BLK; base < count; base += BLK * gridDim.x) {
        int  k      = base + tid;
        bool active = (k < count);
        int  kk     = active ? k : 0;
        int  i      = list[w * CAP + kk];
        float xv = x[i];
        float xn = (xv - mean) * inv_std;

        // input layer: h = tanh(xn*Wi + bi), staged to own LDS column
        #pragma unroll 8
        for (int o = 0; o < NEUR; ++o)
            hbuf[o * BLK + tid] = fast_tanh(fmaf(xn, Wi[o], bi[o]));

        // hidden layer 1: ii ROLLED (unroll 1) -> one 64-float W-row in
        // flight -> scalar loads fit SGPR file, no VGPR pressure.
        float a[NEUR];
        #pragma unroll
        for (int o = 0; o < NEUR; ++o) a[o] = b0[o];
        #pragma unroll 1
        for (int ii = 0; ii < NEUR; ++ii) {
            float hv = hbuf[ii * BLK + tid];
            const float* row = W0 + ii * NEUR;    // uniform addr -> s_load
            #pragma unroll
            for (int o = 0; o < NEUR; ++o)
                a[o] = fmaf(hv, row[o], a[o]);
        }
        #pragma unroll 8
        for (int o = 0; o < NEUR; ++o)
            hbuf[o * BLK + tid] = fast_tanh(a[o]);

        // hidden layer 2
        #pragma unroll
        for (int o = 0; o < NEUR; ++o) a[o] = b1[o];
        #pragma unroll 1
        for (int ii = 0; ii < NEUR; ++ii) {
            float hv = hbuf[ii * BLK + tid];
            const float* row = W1 + ii * NEUR;
            #pragma unroll
            for (int o = 0; o < NEUR; ++o)
                a[o] = fmaf(hv, row[o], a[o]);
        }
        #pragma unroll 8
        for (int o = 0; o < NEUR; ++o)
            hbuf[o * BLK + tid] = fast_tanh(a[o]);

        // output layer
        float outv = bo;
        #pragma unroll 8
        for (int o = 0; o < NEUR; ++o)
            outv = fmaf(hbuf[o * BLK + tid], Wo[o], outv);

        float win = fast_sigmoid((xv - ow0) * 2.0f) *
                    fast_sigmoid((ow1 - xv) * 2.0f);

        if (active) atomicAdd(&out[i], win * outv);
    }
}

extern "C" void kernel_launch(void* const* d_in, const int* in_sizes, int n_in,
                              void* d_out, int out_size, void* d_ws, size_t ws_size,
                              hipStream_t stream) {
    const float* x     = (const float*)d_in[0];
    const float* W_in  = (const float*)d_in[1];
    const float* b_in  = (const float*)d_in[2];
    const float* W_h   = (const float*)d_in[3];
    const float* b_h   = (const float*)d_in[4];
    const float* W_out = (const float*)d_in[5];
    const float* b_out = (const float*)d_in[6];
    float* out = (float*)d_out;
    const int n = in_sizes[0];

    int* cnt  = (int*)d_ws;                     // 16*16 ints (64B/window)
    int* list = (int*)((char*)d_ws + 1024);     // 16*CAP ints

    hipMemsetAsync(cnt, 0, NW * CSTR * sizeof(int), stream);

    pass1_bucket<<<(n + 1023) / 1024, 1024, 0, stream>>>(x, n, cnt, list, out);

    dim3 grid(32, NW);   // 8192 slots/window >= max count ~7.9k
    pass2_mlp<<<grid, BLK, 0, stream>>>(x, W_in, b_in, W_h, b_h, W_out, b_out,
                                        cnt, list, out);
}

// Round 6
// 127.008 us; speedup vs baseline: 1.7339x; 1.7339x over previous
//
#include <hip/hip_runtime.h>

// FBPinn 1D, NW=16 windows, MLP 1->64->64->64->1 (tanh), sigmoid windows.
//   pass1: bucket point indices per window via LDS histogram + one global
//          atomic per (window, block); 1024-thr blocks; zeroes out[].
//   pass2: one window per block-column. Accumulators = FOUR float16
//          ext-vectors (SSA values -> vector phis -> cannot be demoted to
//          scratch). h staged in per-thread LDS column (dynamic ii index ok),
//          weight rows wave-uniform (scalar loads). ii-loop ROLLED (I$-safe).
//   [R2: dynamic h[ii] -> scratch 94MB, 73us]
//   [R3: full unroll -> 40KB body > 32KB I$, VALUBusy 12%, 186us]
//   [R4/R5: rolled loop around float a[64] C-array -> alloca shadow survives,
//           ~1KB/point scratch round-trip, WRITE 120MB, 76-180us. Fix: C-array
//           accumulators are NOT loop-promotable; ext_vector_type is.]
// Workspace: int cnt[16*16] (64B stride/window) @0, int list[16*CAP] @1024.

#define NW    16
#define NEUR  64
#define BLK   256
#define CAP   10240
#define CSTR  16          // cnt stride in ints -> 64B, one cacheline/window

typedef float v16 __attribute__((ext_vector_type(16)));

__device__ __forceinline__ float fast_tanh(float x) {
    float e = __expf(x + x);
    return 1.0f - 2.0f * __builtin_amdgcn_rcpf(e + 1.0f);
}
__device__ __forceinline__ float fast_sigmoid(float z) {
    return __builtin_amdgcn_rcpf(1.0f + __expf(-z));
}

__global__ __launch_bounds__(1024) void pass1_bucket(
    const float* __restrict__ x, int n,
    int* __restrict__ cnt, int* __restrict__ list,
    float* __restrict__ out) {
    __shared__ int lcnt[NW];
    __shared__ int lbase[NW];
    const int tid = threadIdx.x;
    if (tid < NW) lcnt[tid] = 0;
    __syncthreads();

    const int i = blockIdx.x * 1024 + tid;
    int w0 = -1, w1 = -1, p0 = 0, p1 = 0;
    if (i < n) {
        out[i] = 0.0f;                    // fold d_out zeroing into pass1
        float xv = x[i];
        #pragma unroll
        for (int w = 0; w < NW; ++w) {
            float lo = (w == 0)      ? 0.0f   : ((float)w - 0.125f) * 6.25f;
            float hi = (w == NW - 1) ? 100.0f : ((float)w + 1.125f) * 6.25f;
            if (lo < xv && xv < hi) {     // exact strict compares
                if (w0 < 0) w0 = w; else w1 = w;
            }
        }
        if (w0 >= 0) p0 = atomicAdd(&lcnt[w0], 1);
        if (w1 >= 0) p1 = atomicAdd(&lcnt[w1], 1);
    }
    __syncthreads();
    if (tid < NW)
        lbase[tid] = atomicAdd(&cnt[tid * CSTR], lcnt[tid]);
    __syncthreads();

    if (w0 >= 0) { int p = lbase[w0] + p0; if (p < CAP) list[w0 * CAP + p] = i; }
    if (w1 >= 0) { int p = lbase[w1] + p1; if (p < CAP) list[w1 * CAP + p] = i; }
}

__global__ __launch_bounds__(256, 2) void pass2_mlp(
    const float* __restrict__ x,
    const float* __restrict__ W_in, const float* __restrict__ b_in,
    const float* __restrict__ W_h,  const float* __restrict__ b_h,
    const float* __restrict__ W_out, const float* __restrict__ b_out,
    const int* __restrict__ cnt, const int* __restrict__ list,
    float* __restrict__ out) {
    __shared__ float hbuf[NEUR * BLK];            // 64 KB, column per thread
    const int tid = threadIdx.x;
    const int w   = blockIdx.y;                   // window id: wave-uniform
    const int count = min(cnt[w * CSTR], CAP);

    float lo = (w == 0)      ? 0.0f   : ((float)w - 0.125f) * 6.25f;
    float hi = (w == NW - 1) ? 100.0f : ((float)w + 1.125f) * 6.25f;
    float mean    = 0.5f * (lo + hi);
    float inv_std = 1.0f / (0.5f * (hi - lo));
    float ow0 = (float)w * 6.25f;                 // ovm[w] exactly
    float ow1 = (float)(w + 1) * 6.25f;

    const float* Wi = W_in  + w * NEUR;
    const float* bi = b_in  + w * NEUR;
    const float* W0 = W_h   + (0 * NW + w) * NEUR * NEUR;
    const float* b0 = b_h   + (0 * NW + w) * NEUR;
    const float* W1 = W_h   + (1 * NW + w) * NEUR * NEUR;
    const float* b1 = b_h   + (1 * NW + w) * NEUR;
    const float* Wo = W_out + w * NEUR;
    const float bo  = b_out[w];

    for (int base = blockIdx.x * BLK; base < count; base += BLK * gridDim.x) {
        int  k      = base + tid;
        bool active = (k < count);
        int  kk     = active ? k : 0;
        int  i      = list[w * CAP + kk];
        float xv = x[i];
        float xn = (xv - mean) * inv_std;

        // input layer: h = tanh(xn*Wi + bi), staged to own LDS column
        #pragma unroll 8
        for (int o = 0; o < NEUR; ++o)
            hbuf[o * BLK + tid] = fast_tanh(fmaf(xn, Wi[o], bi[o]));

        // ---- hidden layer 1: accumulators in SSA vectors ----
        v16 A0, A1, A2, A3;
        #pragma unroll
        for (int o = 0; o < 16; ++o) {
            A0[o] = b0[o]; A1[o] = b0[16 + o];
            A2[o] = b0[32 + o]; A3[o] = b0[48 + o];
        }
        #pragma unroll 1
        for (int ii = 0; ii < NEUR; ++ii) {
            float hv = hbuf[ii * BLK + tid];
            const float* row = W0 + ii * NEUR;    // uniform addr -> s_load
            #pragma unroll
            for (int o = 0; o < 16; ++o) {
                A0[o] = fmaf(hv, row[o],      A0[o]);
                A1[o] = fmaf(hv, row[16 + o], A1[o]);
                A2[o] = fmaf(hv, row[32 + o], A2[o]);
                A3[o] = fmaf(hv, row[48 + o], A3[o]);
            }
        }
        #pragma unroll 4
        for (int o = 0; o < 16; ++o) {
            hbuf[o * BLK + tid]        = fast_tanh(A0[o]);
            hbuf[(16 + o) * BLK + tid] = fast_tanh(A1[o]);
            hbuf[(32 + o) * BLK + tid] = fast_tanh(A2[o]);
            hbuf[(48 + o) * BLK + tid] = fast_tanh(A3[o]);
        }

        // ---- hidden layer 2 ----
        #pragma unroll
        for (int o = 0; o < 16; ++o) {
            A0[o] = b1[o]; A1[o] = b1[16 + o];
            A2[o] = b1[32 + o]; A3[o] = b1[48 + o];
        }
        #pragma unroll 1
        for (int ii = 0; ii < NEUR; ++ii) {
            float hv = hbuf[ii * BLK + tid];
            const float* row = W1 + ii * NEUR;
            #pragma unroll
            for (int o = 0; o < 16; ++o) {
                A0[o] = fmaf(hv, row[o],      A0[o]);
                A1[o] = fmaf(hv, row[16 + o], A1[o]);
                A2[o] = fmaf(hv, row[32 + o], A2[o]);
                A3[o] = fmaf(hv, row[48 + o], A3[o]);
            }
        }
        #pragma unroll 4
        for (int o = 0; o < 16; ++o) {
            hbuf[o * BLK + tid]        = fast_tanh(A0[o]);
            hbuf[(16 + o) * BLK + tid] = fast_tanh(A1[o]);
            hbuf[(32 + o) * BLK + tid] = fast_tanh(A2[o]);
            hbuf[(48 + o) * BLK + tid] = fast_tanh(A3[o]);
        }

        // output layer
        float outv = bo;
        #pragma unroll 8
        for (int o = 0; o < NEUR; ++o)
            outv = fmaf(hbuf[o * BLK + tid], Wo[o], outv);

        float win = fast_sigmoid((xv - ow0) * 2.0f) *
                    fast_sigmoid((ow1 - xv) * 2.0f);

        if (active) atomicAdd(&out[i], win * outv);
    }
}

extern "C" void kernel_launch(void* const* d_in, const int* in_sizes, int n_in,
                              void* d_out, int out_size, void* d_ws, size_t ws_size,
                              hipStream_t stream) {
    const float* x     = (const float*)d_in[0];
    const float* W_in  = (const float*)d_in[1];
    const float* b_in  = (const float*)d_in[2];
    const float* W_h   = (const float*)d_in[3];
    const float* b_h   = (const float*)d_in[4];
    const float* W_out = (const float*)d_in[5];
    const float* b_out = (const float*)d_in[6];
    float* out = (float*)d_out;
    const int n = in_sizes[0];

    int* cnt  = (int*)d_ws;                     // 16*16 ints (64B/window)
    int* list = (int*)((char*)d_ws + 1024);     // 16*CAP ints

    hipMemsetAsync(cnt, 0, NW * CSTR * sizeof(int), stream);

    pass1_bucket<<<(n + 1023) / 1024, 1024, 0, stream>>>(x, n, cnt, list, out);

    dim3 grid(32, NW);   // 8192 slots/window >= max count ~7.9k
    pass2_mlp<<<grid, BLK, 0, stream>>>(x, W_in, b_in, W_h, b_h, W_out, b_out,
                                        cnt, list, out);
}